// Round 14
// baseline (109.724 us; speedup 1.0000x reference)
//
#include <hip/hip_runtime.h>
#include <math.h>

// Problem constants: B=8, L=2048, T=512, Dh=1024, Dg=768, Dp=256, SCALE=Dp^-0.5
#define BATCH 8
#define LKEYS 2048
#define TQ    512
#define DH    1024
#define DG    768
#define DP    256
#define SCALE 0.0625f

typedef short  short8  __attribute__((ext_vector_type(8)));   // MFMA A/B frag (8 bf16)
typedef float  floatx4 __attribute__((ext_vector_type(4)));   // MFMA C/D frag
typedef unsigned short u16x4 __attribute__((ext_vector_type(4)));
typedef unsigned short u16x8 __attribute__((ext_vector_type(8)));

typedef unsigned int __attribute__((address_space(1))) as1_uint;
typedef unsigned int __attribute__((address_space(3))) as3_uint;

__device__ __forceinline__ unsigned short f2b(float f) {
    union { float f; unsigned int u; } v; v.f = f;
    unsigned int u = v.u;
    unsigned int r = u + 0x7fffu + ((u >> 16) & 1u);   // RNE
    if ((u & 0x7f800000u) == 0x7f800000u) r = u;        // inf/nan passthrough
    return (unsigned short)(r >> 16);
}
__device__ __forceinline__ float b2f(unsigned short b) {
    union { unsigned int u; float f; } v; v.u = ((unsigned int)b) << 16;
    return v.f;
}

// async global->LDS, 16B per lane (lane-linear LDS dest).
__device__ __forceinline__ void gload_lds16(const void* g, void* l) {
    __builtin_amdgcn_global_load_lds((const as1_uint*)g, (as3_uint*)l, 16, 0, 0);
}

// s_waitcnt immediate: vmcnt=vm, expcnt/lgkmcnt = max (don't wait)
__host__ __device__ constexpr int wcnt_vm(int vm) {
    return (vm & 15) | ((vm >> 4) << 14) | (7 << 4) | (15 << 8);
}

// ---------------------------------------------------------------------------
// Pipelined all-bf16 MFMA GEMM: BM x BN tile, 4 waves (2x2), BK=32.
//   PIPE 0: 4 LDS buffers, depth-2, stage(t+2) BEFORE counted vmcnt ->
//           barrier -> MFMA. Proven config (logits, proj).
//   PIPE 2: 3 LDS buffers, depth-2, stage(t+2) AFTER barrier. Race-free:
//           stage(t+2) overwrites buf (t-1)%3 whose readers (iter t-1)
//           finished before barrier_t; vmcnt(NL) pre-barrier keeps one
//           tile in flight (never drains to 0 mid-loop -- R10 lesson).
//           48 KB LDS -> 3 blocks/CU (vs 64 KB -> 2): +50% TLP for Z.
//   OMODE: 0 = C fp32 (+part*sP), 1 = C bf16 (+part*sP), 2 = fp32 scale+mask,
//          3 = bf16 scale+mask (-inf written as 0xFF80)
//   SWZ:   1 = 2D XCD chunk swizzle; 2 = 3D batched (XCD owns whole z-slices)
//   KS:    K-split count; blockIdx.z = part*8 + batch; K arg = per-part K
// A row-major bf16 [M][lda]; B N-major bf16 [N][ldb] (row n = B^T[n][:]).
// sC = per-BATCH stride of C; sP = per-PART stride (R9 bug: don't swap!).
// ---------------------------------------------------------------------------
template<int BM, int BN, int OMODE, int SWZ, int KS, int PIPE>
__global__ __launch_bounds__(256) void gemm_bf16_p(
    const unsigned short* __restrict__ Ap, const unsigned short* __restrict__ Bp,
    const int* __restrict__ maskp, void* __restrict__ Cp,
    int K, int lda, int ldb, int ldc,
    long sA, long sB, long sC, long sM, long sP, float scale)
{
    constexpr int FM = BM / 32, FN = BN / 32;
    constexpr int AI = BM / 64, BI = BN / 64;
    constexpr int NL = AI + BI;
    constexpr int NB = (PIPE == 2) ? 3 : 4;

    __shared__ unsigned short As[NB][BM * 32];
    __shared__ unsigned short Bs[NB][BN * 32];

    int bx = blockIdx.x, by = blockIdx.y, zz = blockIdx.z;
    if (SWZ == 1) {
        const int gx = gridDim.x;
        const int nwg = gx * gridDim.y;         // % 8 == 0
        const int f = by * gx + bx;
        const int nper = nwg >> 3;
        const int fl = (f & 7) * nper + (f >> 3);
        bx = fl % gx; by = fl / gx;
    } else if (SWZ == 2) {
        const int gx = gridDim.x, nxy = gridDim.x * gridDim.y;
        const long l = blockIdx.x + (long)gx * (blockIdx.y + (long)gridDim.y * blockIdx.z);
        const int xcd  = (int)(l & 7);
        const int slot = (int)(l >> 3);
        zz = xcd + 8 * (slot / nxy);            // whole z-slices per XCD
        const int rem = slot % nxy;
        bx = rem % gx; by = rem / gx;
    }
    const int z    = (KS > 1) ? (zz & 7) : zz;      // batch
    const int part = (KS > 1) ? (zz >> 3) : 0;      // K-split part
    const int koff = part * K;

    const int tid  = threadIdx.x;
    const int lane = tid & 63;
    const int wid  = tid >> 6;
    const int wr   = wid >> 1, wc = wid & 1;
    const int lrow = lane & 15;
    const int g    = lane >> 4;

    const unsigned short* A = Ap + (long)z * sA + (long)(by * BM) * lda + koff;
    const unsigned short* B = Bp + (long)z * sB + (long)(bx * BN) * ldb + koff;
    const int srow = tid >> 2, sslot = tid & 3;

    const int nt = K / 32;
    floatx4 acc[FM][FN] = {};

    auto stage = [&](int t, int b) {
        const int k0 = t * 32;
        #pragma unroll
        for (int i = 0; i < AI; ++i)
            gload_lds16(A + (long)(srow + i * 64) * lda + k0 + sslot * 8,
                        (void*)&As[b][(i * 256 + tid) * 8]);
        #pragma unroll
        for (int i = 0; i < BI; ++i)
            gload_lds16(B + (long)(srow + i * 64) * ldb + k0 + sslot * 8,
                        (void*)&Bs[b][(i * 256 + tid) * 8]);
    };

    auto compute = [&](int b) {
        short8 a[FM], bf[FN];
        #pragma unroll
        for (int m = 0; m < FM; ++m)
            a[m] = *(const short8*)&As[b][(wr * (BM / 2) + m * 16 + lrow) * 32 + g * 8];
        #pragma unroll
        for (int n = 0; n < FN; ++n)
            bf[n] = *(const short8*)&Bs[b][(wc * (BN / 2) + n * 16 + lrow) * 32 + g * 8];
        __builtin_amdgcn_s_setprio(1);
        #pragma unroll
        for (int m = 0; m < FM; ++m)
            #pragma unroll
            for (int n = 0; n < FN; ++n)
                acc[m][n] = __builtin_amdgcn_mfma_f32_16x16x32_bf16(
                    a[m], bf[n], acc[m][n], 0, 0, 0);
        __builtin_amdgcn_s_setprio(0);
        __builtin_amdgcn_sched_barrier(0);
    };

    if (PIPE == 0) {
        stage(0, 0);
        stage(1, 1);
        for (int t = 0; t < nt; ++t) {
            if (t + 2 < nt) {
                stage(t + 2, (t + 2) & 3);
                __builtin_amdgcn_s_waitcnt(wcnt_vm(2 * NL));   // my tile-t landed
            } else if (t + 1 < nt) {
                __builtin_amdgcn_s_waitcnt(wcnt_vm(NL));
            } else {
                __builtin_amdgcn_s_waitcnt(wcnt_vm(0));
            }
            __builtin_amdgcn_s_barrier();                      // all waves' tile t landed
            __builtin_amdgcn_sched_barrier(0);
            compute(t & 3);
        }
    } else {
        // PIPE 2: 3-buffer, stage after barrier (depth-2 in flight)
        stage(0, 0);
        stage(1, 1);
        for (int t = 0; t < nt; ++t) {
            if (t + 1 < nt) __builtin_amdgcn_s_waitcnt(wcnt_vm(NL));  // tile t landed
            else            __builtin_amdgcn_s_waitcnt(wcnt_vm(0));
            __builtin_amdgcn_s_barrier();
            __builtin_amdgcn_sched_barrier(0);
            if (t + 2 < nt) stage(t + 2, (t + 2) % 3);  // overwrites buf (t-1)%3: readers done pre-barrier
            __builtin_amdgcn_sched_barrier(0);
            compute(t % 3);
        }
    }

    // ---- epilogue: D row = 4g + reg, col = lrow (m89-verified layout) ----
    const int orow = by * BM + wr * (BM / 2);
    const int ocol = bx * BN + wc * (BN / 2);
    if (OMODE == 0) {
        float* C = (float*)Cp + (long)z * sC + (long)part * sP;
        #pragma unroll
        for (int m = 0; m < FM; ++m)
            #pragma unroll
            for (int n = 0; n < FN; ++n)
                #pragma unroll
                for (int r = 0; r < 4; ++r)
                    C[(long)(orow + m * 16 + 4 * g + r) * ldc + ocol + n * 16 + lrow]
                        = acc[m][n][r];
    } else if (OMODE == 1) {
        unsigned short* C = (unsigned short*)Cp + (long)z * sC + (long)part * sP;
        #pragma unroll
        for (int m = 0; m < FM; ++m)
            #pragma unroll
            for (int n = 0; n < FN; ++n)
                #pragma unroll
                for (int r = 0; r < 4; ++r)
                    C[(long)(orow + m * 16 + 4 * g + r) * ldc + ocol + n * 16 + lrow]
                        = f2b(acc[m][n][r]);
    } else if (OMODE == 2) {
        const int* mask = maskp + (long)z * sM;
        float* C = (float*)Cp + (long)z * sC;
        #pragma unroll
        for (int n = 0; n < FN; ++n) {
            int c = ocol + n * 16 + lrow;
            bool masked = (mask[c] != 0);
            #pragma unroll
            for (int m = 0; m < FM; ++m)
                #pragma unroll
                for (int r = 0; r < 4; ++r)
                    C[(long)(orow + m * 16 + 4 * g + r) * ldc + c]
                        = masked ? -INFINITY : acc[m][n][r] * scale;
        }
    } else {                                   // OMODE 3: bf16 + scale + mask
        const int* mask = maskp + (long)z * sM;
        unsigned short* C = (unsigned short*)Cp + (long)z * sC;
        #pragma unroll
        for (int n = 0; n < FN; ++n) {
            int c = ocol + n * 16 + lrow;
            bool masked = (mask[c] != 0);
            #pragma unroll
            for (int m = 0; m < FM; ++m)
                #pragma unroll
                for (int r = 0; r < 4; ++r)
                    C[(long)(orow + m * 16 + 4 * g + r) * ldc + c]
                        = masked ? (unsigned short)0xFF80u       // -inf bf16
                                 : f2b(acc[m][n][r] * scale);
        }
    }
}

// ---------------------------------------------------------------------------
// Merged K-proj + Q-proj + Hb->HbT transpose, one launch (4736 blocks, 1D):
//   id <  640 : proj blocks (K = Hb@WkT^T for by<128, else Q = Gb@WqT^T),
//               BM=128 BN=64, depth-2 counted-vmcnt loop, 2D XCD swizzle.
//   id >= 640 : 4096 transpose blocks (64x64 bf16 tiles) writing HbT [B,Dh,L]
//               from Hb. HBM-bound work that OVERLAPS the latency-bound proj
//               blocks (proj runs at ~1.6 TB/s, leaving >4 TB/s idle).
// HbT is consumed 3 launches later (Z) -> stream order suffices.
// ---------------------------------------------------------------------------
#define NPROJ 640

__global__ __launch_bounds__(256) void proj_kq_ht(
    const unsigned short* __restrict__ Hb, const unsigned short* __restrict__ WkT,
    unsigned short* __restrict__ Kb,
    const unsigned short* __restrict__ Gb, const unsigned short* __restrict__ WqT,
    unsigned short* __restrict__ Qb,
    unsigned short* __restrict__ HbT)
{
    __shared__ unsigned short smem[4 * 128 * 32 + 4 * 64 * 32];   // 48 KB
    const int tid = threadIdx.x;

    if (blockIdx.x >= NPROJ) {
        // ---- Hb [B,L,Dh] -> HbT [B,Dh,L], 64x64 bf16 tiles ----
        auto ts = (unsigned short(*)[68])smem;                    // [64][68]
        const int b  = blockIdx.x - NPROJ;       // [0, 4096)
        const int z  = b >> 9;                    // 512 tiles per batch
        const int r_ = b & 511;
        const int l0 = (r_ >> 4) << 6;            // 32 l-tiles
        const int d0 = (r_ & 15) << 6;            // 16 d-tiles
        const unsigned short* Hz = Hb + (long)z * LKEYS * DH;
        unsigned short* Tz = HbT + (long)z * DH * LKEYS;
        #pragma unroll
        for (int j = 0; j < 4; ++j) {
            int idx = tid + j * 256, r = idx >> 4, c4 = idx & 15;
            *(u16x4*)&ts[r][4 * c4] = *(const u16x4*)&Hz[(long)(l0 + r) * DH + d0 + 4 * c4];
        }
        __syncthreads();
        #pragma unroll
        for (int j = 0; j < 4; ++j) {
            int idx = tid + j * 256, r = idx >> 4, c4 = idx & 15;  // r = d-row
            u16x4 o;
            o[0] = ts[4 * c4 + 0][r]; o[1] = ts[4 * c4 + 1][r];
            o[2] = ts[4 * c4 + 2][r]; o[3] = ts[4 * c4 + 3][r];
            *(u16x4*)&Tz[(long)(d0 + r) * LKEYS + l0 + 4 * c4] = o;
        }
        return;
    }

    // ---- proj path ----
    constexpr int FM = 4, FN = 2, AI = 2, NL = 3;
    auto As = (unsigned short(*)[128 * 32])smem;
    auto Bs = (unsigned short(*)[64 * 32])(smem + 4 * 128 * 32);

    // 2D chunk swizzle over 640 proj blocks: 80 blocks/XCD
    const int f  = blockIdx.x;
    const int fl = (f & 7) * 80 + (f >> 3);
    const int bx = fl & 3, by = fl >> 2;

    const unsigned short *A, *B;
    unsigned short* C;
    int K, ld;
    if (by < 128) { A = Hb + (long)by * 128 * DH;          B = WkT; C = Kb; K = DH; ld = DH; }
    else          { A = Gb + (long)(by - 128) * 128 * DG;  B = WqT; C = Qb; K = DG; ld = DG; }
    B += (long)bx * 64 * ld;
    const int orow0 = (by < 128) ? by * 128 : (by - 128) * 128;

    const int lane = tid & 63;
    const int wid  = tid >> 6;
    const int wr   = wid >> 1, wc = wid & 1;
    const int lrow = lane & 15;
    const int g    = lane >> 4;
    const int srow = tid >> 2, sslot = tid & 3;

    const int nt = K / 32;
    floatx4 acc[FM][FN] = {};

    auto stage = [&](int t, int b) {
        const int k0 = t * 32;
        #pragma unroll
        for (int i = 0; i < AI; ++i)
            gload_lds16(A + (long)(srow + i * 64) * ld + k0 + sslot * 8,
                        (void*)&As[b][(i * 256 + tid) * 8]);
        gload_lds16(B + (long)srow * ld + k0 + sslot * 8,
                    (void*)&Bs[b][tid * 8]);
    };

    stage(0, 0);
    stage(1, 1);
    for (int t = 0; t < nt; ++t) {
        if (t + 2 < nt) {
            stage(t + 2, (t + 2) & 3);
            __builtin_amdgcn_s_waitcnt(wcnt_vm(2 * NL));
        } else if (t + 1 < nt) {
            __builtin_amdgcn_s_waitcnt(wcnt_vm(NL));
        } else {
            __builtin_amdgcn_s_waitcnt(wcnt_vm(0));
        }
        __builtin_amdgcn_s_barrier();
        __builtin_amdgcn_sched_barrier(0);

        const int b = t & 3;
        short8 a[FM], bf[FN];
        #pragma unroll
        for (int m = 0; m < FM; ++m)
            a[m] = *(const short8*)&As[b][(wr * 64 + m * 16 + lrow) * 32 + g * 8];
        #pragma unroll
        for (int n = 0; n < FN; ++n)
            bf[n] = *(const short8*)&Bs[b][(wc * 32 + n * 16 + lrow) * 32 + g * 8];
        __builtin_amdgcn_s_setprio(1);
        #pragma unroll
        for (int m = 0; m < FM; ++m)
            #pragma unroll
            for (int n = 0; n < FN; ++n)
                acc[m][n] = __builtin_amdgcn_mfma_f32_16x16x32_bf16(
                    a[m], bf[n], acc[m][n], 0, 0, 0);
        __builtin_amdgcn_s_setprio(0);
        __builtin_amdgcn_sched_barrier(0);
    }

    const int orow = orow0 + wr * 64;
    const int ocol = bx * 64 + wc * 32;
    #pragma unroll
    for (int m = 0; m < FM; ++m)
        #pragma unroll
        for (int n = 0; n < FN; ++n)
            #pragma unroll
            for (int r = 0; r < 4; ++r)
                C[(long)(orow + m * 16 + 4 * g + r) * DP + ocol + n * 16 + lrow]
                    = f2b(acc[m][n][r]);
}

// ---------------------------------------------------------------------------
// Fused prep: flat-stream H->Hb (8192 blocks) + G->Gb (1536) +
// Wk->WkT (256) + Wq->WqT (192).
// ---------------------------------------------------------------------------
#define NHS_BLK 8192
#define NG_BLK  1536
#define NWK_BLK 256
#define NWQ_BLK 192

__global__ __launch_bounds__(256) void prep_all(
    const float* __restrict__ H, const float* __restrict__ G,
    const float* __restrict__ Wk, const float* __restrict__ Wq,
    unsigned short* __restrict__ Hb, unsigned short* __restrict__ Gb,
    unsigned short* __restrict__ WkT, unsigned short* __restrict__ WqT)
{
    __shared__ float tf[32][33];
    const int id = blockIdx.x;

    if (id < NHS_BLK + NG_BLK) {
        const float* src; unsigned short* dst; long base;
        if (id < NHS_BLK) { src = H; dst = Hb; base = (long)id * 2048; }
        else              { src = G; dst = Gb; base = (long)(id - NHS_BLK) * 2048; }
        long i = base + (long)threadIdx.x * 8;
        float4 a = *(const float4*)&src[i];
        float4 b = *(const float4*)&src[i + 4];
        u16x8 w;
        w[0] = f2b(a.x); w[1] = f2b(a.y); w[2] = f2b(a.z); w[3] = f2b(a.w);
        w[4] = f2b(b.x); w[5] = f2b(b.y); w[6] = f2b(b.z); w[7] = f2b(b.w);
        *(u16x8*)&dst[i] = w;
    } else {
        const float* W; unsigned short* WT; int D, d0, p0;
        if (id < NHS_BLK + NG_BLK + NWK_BLK) {
            const int bid = id - NHS_BLK - NG_BLK;
            W = Wk; WT = WkT; D = DH;
            d0 = (bid & 31) * 32; p0 = (bid >> 5) * 32;     // 32 x 8
        } else {
            const int bid = id - NHS_BLK - NG_BLK - NWK_BLK;
            W = Wq; WT = WqT; D = DG;
            d0 = (bid % 24) * 32; p0 = (bid / 24) * 32;     // 24 x 8
        }
        const int tx = threadIdx.x & 31, ty = threadIdx.x >> 5;
        #pragma unroll
        for (int j = 0; j < 4; ++j)
            tf[ty + 8 * j][tx] = W[(long)(d0 + ty + 8 * j) * DP + p0 + tx];
        __syncthreads();
        #pragma unroll
        for (int j = 0; j < 4; ++j)
            WT[(long)(p0 + ty + 8 * j) * D + d0 + tx] = f2b(tf[tx][ty + 8 * j]);
    }
}

// ---------------------------------------------------------------------------
// Z = sum of 4 bf16 partials -> fp32. 8 elems/thread. (R10-proven.)
// ---------------------------------------------------------------------------
__global__ __launch_bounds__(256) void reduce_add4(
    const unsigned short* __restrict__ P, long sP, float* __restrict__ Zo)
{
    long i = ((long)blockIdx.x * 256 + threadIdx.x) * 8;
    u16x8 a = *(const u16x8*)&P[i];
    u16x8 b = *(const u16x8*)&P[i + sP];
    u16x8 c = *(const u16x8*)&P[i + 2 * sP];
    u16x8 d = *(const u16x8*)&P[i + 3 * sP];
    float4 o0, o1;
    o0.x = (b2f(a[0]) + b2f(b[0])) + (b2f(c[0]) + b2f(d[0]));
    o0.y = (b2f(a[1]) + b2f(b[1])) + (b2f(c[1]) + b2f(d[1]));
    o0.z = (b2f(a[2]) + b2f(b[2])) + (b2f(c[2]) + b2f(d[2]));
    o0.w = (b2f(a[3]) + b2f(b[3])) + (b2f(c[3]) + b2f(d[3]));
    o1.x = (b2f(a[4]) + b2f(b[4])) + (b2f(c[4]) + b2f(d[4]));
    o1.y = (b2f(a[5]) + b2f(b[5])) + (b2f(c[5]) + b2f(d[5]));
    o1.z = (b2f(a[6]) + b2f(b[6])) + (b2f(c[6]) + b2f(d[6]));
    o1.w = (b2f(a[7]) + b2f(b[7])) + (b2f(c[7]) + b2f(d[7]));
    *(float4*)&Zo[i] = o0;
    *(float4*)&Zo[i + 4] = o1;
}

// ---------------------------------------------------------------------------
// Row softmax over bf16 logits: 2048/row, 256 threads, 8 elems/thread.
// ---------------------------------------------------------------------------
__global__ __launch_bounds__(256) void softmax_kernel(
    const unsigned short* __restrict__ S, unsigned short* __restrict__ Ab)
{
    const u16x8* row8 = (const u16x8*)(S + (long)blockIdx.x * LKEYS);
    u16x8* out8 = (u16x8*)(Ab + (long)blockIdx.x * LKEYS);
    const int tid = threadIdx.x;
    __shared__ float red[4];

    u16x8 v = row8[tid];
    float x[8];
    #pragma unroll
    for (int j = 0; j < 8; ++j) x[j] = b2f(v[j]);

    float m = fmaxf(fmaxf(fmaxf(x[0], x[1]), fmaxf(x[2], x[3])),
                    fmaxf(fmaxf(x[4], x[5]), fmaxf(x[6], x[7])));
    #pragma unroll
    for (int off = 32; off > 0; off >>= 1) m = fmaxf(m, __shfl_xor(m, off));
    if ((tid & 63) == 0) red[tid >> 6] = m;
    __syncthreads();
    m = fmaxf(fmaxf(red[0], red[1]), fmaxf(red[2], red[3]));

    float e[8], s = 0.f;
    #pragma unroll
    for (int j = 0; j < 8; ++j) { e[j] = __expf(x[j] - m); s += e[j]; }
    #pragma unroll
    for (int off = 32; off > 0; off >>= 1) s += __shfl_xor(s, off);
    __syncthreads();
    if ((tid & 63) == 0) red[tid >> 6] = s;
    __syncthreads();
    s = red[0] + red[1] + red[2] + red[3];

    float inv = 1.0f / s;
    u16x8 o;
    #pragma unroll
    for (int j = 0; j < 8; ++j) o[j] = f2b(e[j] * inv);
    out8[tid] = o;
}

// ---------------------------------------------------------------------------
extern "C" void kernel_launch(void* const* d_in, const int* in_sizes, int n_in,
                              void* d_out, int out_size, void* d_ws, size_t ws_size,
                              hipStream_t stream)
{
    const float* H    = (const float*)d_in[0];  // [B,L,Dh]
    const float* G    = (const float*)d_in[1];  // [B,T,Dg]
    const int*   mask = (const int*)  d_in[2];  // [B,L]
    const float* Wk   = (const float*)d_in[3];  // [Dh,Dp]
    const float* Wq   = (const float*)d_in[4];  // [Dg,Dp]
    float*       Z    = (float*)d_out;          // [B,T,Dh]

    // Workspace (101.6 MB). u16 offsets:
    // WkT|WqT|Ab|Kb|Qb|Gb|HbT|X  where X (33.5 MB) = Hb -> S(bf16) -> Zp(4x bf16)
    unsigned short* WkT = (unsigned short*)d_ws;      // 256*1024
    unsigned short* WqT = WkT + 262144;               // 256*768
    unsigned short* Ab  = WqT + 196608;               // 8*512*2048 bf16
    unsigned short* Kb  = Ab  + 8388608;              // 8*2048*256
    unsigned short* Qb  = Kb  + 4194304;              // 8*512*256
    unsigned short* Gb  = Qb  + 1048576;              // 8*512*768
    unsigned short* HbT = Gb  + 3145728;              // 8*1024*2048
    unsigned short* Hb  = HbT + 16777216;             // X: 8*2048*1024 u16
    unsigned short* S   = Hb;                         // X: 8*512*2048 u16 (bf16)
    unsigned short* Zp  = Hb;                         // X: 4 * 8*512*1024 u16
    const long sZp = (long)BATCH * TQ * DH;           // per-PART stride (u16 elems)
    const long sZb = (long)TQ * DH;                   // per-BATCH stride (u16 elems)

    // 1) prep: flat H->Hb, G->Gb, W transposes
    prep_all<<<NHS_BLK + NG_BLK + NWK_BLK + NWQ_BLK, 256, 0, stream>>>(
        H, G, Wk, Wq, Hb, Gb, WkT, WqT);

    // 2) K-proj + Q-proj + Hb->HbT transpose (overlapped): 640 + 4096 blocks.
    proj_kq_ht<<<NPROJ + 4096, 256, 0, stream>>>(Hb, WkT, Kb, Gb, WqT, Qb, HbT);

    // 3) logits -> S bf16 (scale+mask) : per batch 512x2048x256. 3D swz.
    gemm_bf16_p<128, 128, 3, 2, 1, 0><<<dim3(16, 4, BATCH), 256, 0, stream>>>(
        Qb, Kb, mask, S, DP, DP, DP, LKEYS,
        (long)TQ * DP, (long)LKEYS * DP, (long)TQ * LKEYS, (long)LKEYS, 0, SCALE);

    // 4) softmax over L (bf16 in) -> bf16 alpha (S dead after; Zp overlays X)
    softmax_kernel<<<BATCH * TQ, 256, 0, stream>>>(S, Ab);

    // 5) Z partials = Ab @ HbT^T, KSPLIT=4, PIPE=2 (3-buf, 48 KB -> 3 blk/CU):
    // per (batch,part) 512x1024x512. 1024 blocks, 3D swz, bf16 partials.
    gemm_bf16_p<128, 128, 1, 2, 4, 2><<<dim3(8, 4, 4 * BATCH), 256, 0, stream>>>(
        Ab, HbT, nullptr, Zp, LKEYS / 4, LKEYS, LKEYS, DH,
        (long)TQ * LKEYS, (long)DH * LKEYS, sZb, 0, sZp, 1.f);

    // 6) Z = sum of 4 partials
    reduce_add4<<<(int)(sZp / 8 / 256), 256, 0, stream>>>(Zp, sZp, Z);
}

// Round 15
// 101.529 us; speedup vs baseline: 1.0807x; 1.0807x over previous
//
#include <hip/hip_runtime.h>
#include <math.h>

// Problem constants: B=8, L=2048, T=512, Dh=1024, Dg=768, Dp=256, SCALE=Dp^-0.5
#define BATCH 8
#define LKEYS 2048
#define TQ    512
#define DH    1024
#define DG    768
#define DP    256
#define SCALE 0.0625f

typedef short  short8  __attribute__((ext_vector_type(8)));   // MFMA A/B frag (8 bf16)
typedef float  floatx4 __attribute__((ext_vector_type(4)));   // MFMA C/D frag
typedef unsigned short u16x4 __attribute__((ext_vector_type(4)));
typedef unsigned short u16x8 __attribute__((ext_vector_type(8)));

typedef unsigned int __attribute__((address_space(1))) as1_uint;
typedef unsigned int __attribute__((address_space(3))) as3_uint;

__device__ __forceinline__ unsigned short f2b(float f) {
    union { float f; unsigned int u; } v; v.f = f;
    unsigned int u = v.u;
    unsigned int r = u + 0x7fffu + ((u >> 16) & 1u);   // RNE
    if ((u & 0x7f800000u) == 0x7f800000u) r = u;        // inf/nan passthrough
    return (unsigned short)(r >> 16);
}
__device__ __forceinline__ float b2f(unsigned short b) {
    union { unsigned int u; float f; } v; v.u = ((unsigned int)b) << 16;
    return v.f;
}

// async global->LDS, 16B per lane (lane-linear LDS dest).
__device__ __forceinline__ void gload_lds16(const void* g, void* l) {
    __builtin_amdgcn_global_load_lds((const as1_uint*)g, (as3_uint*)l, 16, 0, 0);
}

// s_waitcnt immediate: vmcnt=vm, expcnt/lgkmcnt = max (don't wait)
__host__ __device__ constexpr int wcnt_vm(int vm) {
    return (vm & 15) | ((vm >> 4) << 14) | (7 << 4) | (15 << 8);
}

// ---------------------------------------------------------------------------
// Pipelined all-bf16 MFMA GEMM: BM x BN tile, 4 waves (2x2), BK=32,
// 4 LDS buffers, DEPTH-2, stage(t+2) -> counted vmcnt (never 0 in steady
// state) -> barrier -> MFMA. This is the proven local optimum:
//   R10/R14: per-iter vmcnt(0) or 1-tile-in-flight (stage-after-barrier)
//            exposes full load latency regardless of occupancy gains.
//   R6: stage-after-barrier puts addr calc on the critical path.
//   R13-best: Z @ KS=2 here = ~570 TF ~= 94% of the 2-phase structure
//            ceiling (m233 ~607 TF). Depth-2 + 4buf + KS=2 stays.
//   OMODE: 0 = C fp32 (+part*sP), 1 = C bf16 (+part*sP), 2 = fp32 scale+mask,
//          3 = bf16 scale+mask (-inf written as 0xFF80)
//   SWZ:   1 = 2D XCD chunk swizzle; 2 = 3D batched (XCD owns whole z-slices)
//   KS:    K-split count; blockIdx.z = part*8 + batch; K arg = per-part K
// A row-major bf16 [M][lda]; B N-major bf16 [N][ldb] (row n = B^T[n][:]).
// sC = per-BATCH stride of C; sP = per-PART stride (R9 bug: don't swap!).
// ---------------------------------------------------------------------------
template<int BM, int BN, int OMODE, int SWZ, int KS>
__global__ __launch_bounds__(256) void gemm_bf16_p(
    const unsigned short* __restrict__ Ap, const unsigned short* __restrict__ Bp,
    const int* __restrict__ maskp, void* __restrict__ Cp,
    int K, int lda, int ldb, int ldc,
    long sA, long sB, long sC, long sM, long sP, float scale)
{
    constexpr int FM = BM / 32, FN = BN / 32;
    constexpr int AI = BM / 64, BI = BN / 64;
    constexpr int NL = AI + BI;

    __shared__ unsigned short As[4][BM * 32];
    __shared__ unsigned short Bs[4][BN * 32];

    int bx = blockIdx.x, by = blockIdx.y, zz = blockIdx.z;
    if (SWZ == 1) {
        const int gx = gridDim.x;
        const int nwg = gx * gridDim.y;         // % 8 == 0
        const int f = by * gx + bx;
        const int nper = nwg >> 3;
        const int fl = (f & 7) * nper + (f >> 3);
        bx = fl % gx; by = fl / gx;
    } else if (SWZ == 2) {
        const int gx = gridDim.x, nxy = gridDim.x * gridDim.y;
        const long l = blockIdx.x + (long)gx * (blockIdx.y + (long)gridDim.y * blockIdx.z);
        const int xcd  = (int)(l & 7);
        const int slot = (int)(l >> 3);
        zz = xcd + 8 * (slot / nxy);            // whole z-slices per XCD
        const int rem = slot % nxy;
        bx = rem % gx; by = rem / gx;
    }
    const int z    = (KS > 1) ? (zz & 7) : zz;      // batch
    const int part = (KS > 1) ? (zz >> 3) : 0;      // K-split part
    const int koff = part * K;

    const int tid  = threadIdx.x;
    const int lane = tid & 63;
    const int wid  = tid >> 6;
    const int wr   = wid >> 1, wc = wid & 1;
    const int lrow = lane & 15;
    const int g    = lane >> 4;

    const unsigned short* A = Ap + (long)z * sA + (long)(by * BM) * lda + koff;
    const unsigned short* B = Bp + (long)z * sB + (long)(bx * BN) * ldb + koff;
    const int srow = tid >> 2, sslot = tid & 3;

    const int nt = K / 32;
    floatx4 acc[FM][FN] = {};

    auto stage = [&](int t, int b) {
        const int k0 = t * 32;
        #pragma unroll
        for (int i = 0; i < AI; ++i)
            gload_lds16(A + (long)(srow + i * 64) * lda + k0 + sslot * 8,
                        (void*)&As[b][(i * 256 + tid) * 8]);
        #pragma unroll
        for (int i = 0; i < BI; ++i)
            gload_lds16(B + (long)(srow + i * 64) * ldb + k0 + sslot * 8,
                        (void*)&Bs[b][(i * 256 + tid) * 8]);
    };

    stage(0, 0);
    stage(1, 1);
    for (int t = 0; t < nt; ++t) {
        if (t + 2 < nt) {
            stage(t + 2, (t + 2) & 3);
            __builtin_amdgcn_s_waitcnt(wcnt_vm(2 * NL));   // my tile-t landed
        } else if (t + 1 < nt) {
            __builtin_amdgcn_s_waitcnt(wcnt_vm(NL));
        } else {
            __builtin_amdgcn_s_waitcnt(wcnt_vm(0));
        }
        __builtin_amdgcn_s_barrier();                      // all waves' tile t landed
        __builtin_amdgcn_sched_barrier(0);

        const int b = t & 3;
        short8 a[FM], bf[FN];
        #pragma unroll
        for (int m = 0; m < FM; ++m)
            a[m] = *(const short8*)&As[b][(wr * (BM / 2) + m * 16 + lrow) * 32 + g * 8];
        #pragma unroll
        for (int n = 0; n < FN; ++n)
            bf[n] = *(const short8*)&Bs[b][(wc * (BN / 2) + n * 16 + lrow) * 32 + g * 8];
        __builtin_amdgcn_s_setprio(1);
        #pragma unroll
        for (int m = 0; m < FM; ++m)
            #pragma unroll
            for (int n = 0; n < FN; ++n)
                acc[m][n] = __builtin_amdgcn_mfma_f32_16x16x32_bf16(
                    a[m], bf[n], acc[m][n], 0, 0, 0);
        __builtin_amdgcn_s_setprio(0);
        __builtin_amdgcn_sched_barrier(0);
    }

    // ---- epilogue: D row = 4g + reg, col = lrow (m89-verified layout) ----
    const int orow = by * BM + wr * (BM / 2);
    const int ocol = bx * BN + wc * (BN / 2);
    if (OMODE == 0) {
        float* C = (float*)Cp + (long)z * sC + (long)part * sP;
        #pragma unroll
        for (int m = 0; m < FM; ++m)
            #pragma unroll
            for (int n = 0; n < FN; ++n)
                #pragma unroll
                for (int r = 0; r < 4; ++r)
                    C[(long)(orow + m * 16 + 4 * g + r) * ldc + ocol + n * 16 + lrow]
                        = acc[m][n][r];
    } else if (OMODE == 1) {
        unsigned short* C = (unsigned short*)Cp + (long)z * sC + (long)part * sP;
        #pragma unroll
        for (int m = 0; m < FM; ++m)
            #pragma unroll
            for (int n = 0; n < FN; ++n)
                #pragma unroll
                for (int r = 0; r < 4; ++r)
                    C[(long)(orow + m * 16 + 4 * g + r) * ldc + ocol + n * 16 + lrow]
                        = f2b(acc[m][n][r]);
    } else if (OMODE == 2) {
        const int* mask = maskp + (long)z * sM;
        float* C = (float*)Cp + (long)z * sC;
        #pragma unroll
        for (int n = 0; n < FN; ++n) {
            int c = ocol + n * 16 + lrow;
            bool masked = (mask[c] != 0);
            #pragma unroll
            for (int m = 0; m < FM; ++m)
                #pragma unroll
                for (int r = 0; r < 4; ++r)
                    C[(long)(orow + m * 16 + 4 * g + r) * ldc + c]
                        = masked ? -INFINITY : acc[m][n][r] * scale;
        }
    } else {                                   // OMODE 3: bf16 + scale + mask
        const int* mask = maskp + (long)z * sM;
        unsigned short* C = (unsigned short*)Cp + (long)z * sC;
        #pragma unroll
        for (int n = 0; n < FN; ++n) {
            int c = ocol + n * 16 + lrow;
            bool masked = (mask[c] != 0);
            #pragma unroll
            for (int m = 0; m < FM; ++m)
                #pragma unroll
                for (int r = 0; r < 4; ++r)
                    C[(long)(orow + m * 16 + 4 * g + r) * ldc + c]
                        = masked ? (unsigned short)0xFF80u       // -inf bf16
                                 : f2b(acc[m][n][r] * scale);
        }
    }
}

// ---------------------------------------------------------------------------
// Merged K-proj + Q-proj + Hb->HbT transpose, one launch (4736 blocks, 1D):
//   id <  640 : proj blocks (K = Hb@WkT^T for by<128, else Q = Gb@WqT^T),
//               BM=128 BN=64, depth-2 counted-vmcnt loop, 2D XCD swizzle.
//   id >= 640 : 4096 transpose blocks (64x64 bf16 tiles) writing HbT [B,Dh,L]
//               from Hb. HBM-bound work that OVERLAPS the latency-bound proj
//               blocks (proj runs at ~1.6 TB/s, leaving >4 TB/s idle).
// HbT is consumed 3 launches later (Z) -> stream order suffices.
// ---------------------------------------------------------------------------
#define NPROJ 640

__global__ __launch_bounds__(256) void proj_kq_ht(
    const unsigned short* __restrict__ Hb, const unsigned short* __restrict__ WkT,
    unsigned short* __restrict__ Kb,
    const unsigned short* __restrict__ Gb, const unsigned short* __restrict__ WqT,
    unsigned short* __restrict__ Qb,
    unsigned short* __restrict__ HbT)
{
    __shared__ unsigned short smem[4 * 128 * 32 + 4 * 64 * 32];   // 48 KB
    const int tid = threadIdx.x;

    if (blockIdx.x >= NPROJ) {
        // ---- Hb [B,L,Dh] -> HbT [B,Dh,L], 64x64 bf16 tiles ----
        auto ts = (unsigned short(*)[68])smem;                    // [64][68]
        const int b  = blockIdx.x - NPROJ;       // [0, 4096)
        const int z  = b >> 9;                    // 512 tiles per batch
        const int r_ = b & 511;
        const int l0 = (r_ >> 4) << 6;            // 32 l-tiles
        const int d0 = (r_ & 15) << 6;            // 16 d-tiles
        const unsigned short* Hz = Hb + (long)z * LKEYS * DH;
        unsigned short* Tz = HbT + (long)z * DH * LKEYS;
        #pragma unroll
        for (int j = 0; j < 4; ++j) {
            int idx = tid + j * 256, r = idx >> 4, c4 = idx & 15;
            *(u16x4*)&ts[r][4 * c4] = *(const u16x4*)&Hz[(long)(l0 + r) * DH + d0 + 4 * c4];
        }
        __syncthreads();
        #pragma unroll
        for (int j = 0; j < 4; ++j) {
            int idx = tid + j * 256, r = idx >> 4, c4 = idx & 15;  // r = d-row
            u16x4 o;
            o[0] = ts[4 * c4 + 0][r]; o[1] = ts[4 * c4 + 1][r];
            o[2] = ts[4 * c4 + 2][r]; o[3] = ts[4 * c4 + 3][r];
            *(u16x4*)&Tz[(long)(d0 + r) * LKEYS + l0 + 4 * c4] = o;
        }
        return;
    }

    // ---- proj path ----
    constexpr int FM = 4, FN = 2, AI = 2, NL = 3;
    auto As = (unsigned short(*)[128 * 32])smem;
    auto Bs = (unsigned short(*)[64 * 32])(smem + 4 * 128 * 32);

    // 2D chunk swizzle over 640 proj blocks: 80 blocks/XCD
    const int f  = blockIdx.x;
    const int fl = (f & 7) * 80 + (f >> 3);
    const int bx = fl & 3, by = fl >> 2;

    const unsigned short *A, *B;
    unsigned short* C;
    int K, ld;
    if (by < 128) { A = Hb + (long)by * 128 * DH;          B = WkT; C = Kb; K = DH; ld = DH; }
    else          { A = Gb + (long)(by - 128) * 128 * DG;  B = WqT; C = Qb; K = DG; ld = DG; }
    B += (long)bx * 64 * ld;
    const int orow0 = (by < 128) ? by * 128 : (by - 128) * 128;

    const int lane = tid & 63;
    const int wid  = tid >> 6;
    const int wr   = wid >> 1, wc = wid & 1;
    const int lrow = lane & 15;
    const int g    = lane >> 4;
    const int srow = tid >> 2, sslot = tid & 3;

    const int nt = K / 32;
    floatx4 acc[FM][FN] = {};

    auto stage = [&](int t, int b) {
        const int k0 = t * 32;
        #pragma unroll
        for (int i = 0; i < AI; ++i)
            gload_lds16(A + (long)(srow + i * 64) * ld + k0 + sslot * 8,
                        (void*)&As[b][(i * 256 + tid) * 8]);
        gload_lds16(B + (long)srow * ld + k0 + sslot * 8,
                    (void*)&Bs[b][tid * 8]);
    };

    stage(0, 0);
    stage(1, 1);
    for (int t = 0; t < nt; ++t) {
        if (t + 2 < nt) {
            stage(t + 2, (t + 2) & 3);
            __builtin_amdgcn_s_waitcnt(wcnt_vm(2 * NL));
        } else if (t + 1 < nt) {
            __builtin_amdgcn_s_waitcnt(wcnt_vm(NL));
        } else {
            __builtin_amdgcn_s_waitcnt(wcnt_vm(0));
        }
        __builtin_amdgcn_s_barrier();
        __builtin_amdgcn_sched_barrier(0);

        const int b = t & 3;
        short8 a[FM], bf[FN];
        #pragma unroll
        for (int m = 0; m < FM; ++m)
            a[m] = *(const short8*)&As[b][(wr * 64 + m * 16 + lrow) * 32 + g * 8];
        #pragma unroll
        for (int n = 0; n < FN; ++n)
            bf[n] = *(const short8*)&Bs[b][(wc * 32 + n * 16 + lrow) * 32 + g * 8];
        __builtin_amdgcn_s_setprio(1);
        #pragma unroll
        for (int m = 0; m < FM; ++m)
            #pragma unroll
            for (int n = 0; n < FN; ++n)
                acc[m][n] = __builtin_amdgcn_mfma_f32_16x16x32_bf16(
                    a[m], bf[n], acc[m][n], 0, 0, 0);
        __builtin_amdgcn_s_setprio(0);
        __builtin_amdgcn_sched_barrier(0);
    }

    const int orow = orow0 + wr * 64;
    const int ocol = bx * 64 + wc * 32;
    #pragma unroll
    for (int m = 0; m < FM; ++m)
        #pragma unroll
        for (int n = 0; n < FN; ++n)
            #pragma unroll
            for (int r = 0; r < 4; ++r)
                C[(long)(orow + m * 16 + 4 * g + r) * DP + ocol + n * 16 + lrow]
                    = f2b(acc[m][n][r]);
}

// ---------------------------------------------------------------------------
// Fused prep: flat-stream H->Hb (8192 blocks) + G->Gb (1536) +
// Wk->WkT (256) + Wq->WqT (192).
// ---------------------------------------------------------------------------
#define NHS_BLK 8192
#define NG_BLK  1536
#define NWK_BLK 256
#define NWQ_BLK 192

__global__ __launch_bounds__(256) void prep_all(
    const float* __restrict__ H, const float* __restrict__ G,
    const float* __restrict__ Wk, const float* __restrict__ Wq,
    unsigned short* __restrict__ Hb, unsigned short* __restrict__ Gb,
    unsigned short* __restrict__ WkT, unsigned short* __restrict__ WqT)
{
    __shared__ float tf[32][33];
    const int id = blockIdx.x;

    if (id < NHS_BLK + NG_BLK) {
        const float* src; unsigned short* dst; long base;
        if (id < NHS_BLK) { src = H; dst = Hb; base = (long)id * 2048; }
        else              { src = G; dst = Gb; base = (long)(id - NHS_BLK) * 2048; }
        long i = base + (long)threadIdx.x * 8;
        float4 a = *(const float4*)&src[i];
        float4 b = *(const float4*)&src[i + 4];
        u16x8 w;
        w[0] = f2b(a.x); w[1] = f2b(a.y); w[2] = f2b(a.z); w[3] = f2b(a.w);
        w[4] = f2b(b.x); w[5] = f2b(b.y); w[6] = f2b(b.z); w[7] = f2b(b.w);
        *(u16x8*)&dst[i] = w;
    } else {
        const float* W; unsigned short* WT; int D, d0, p0;
        if (id < NHS_BLK + NG_BLK + NWK_BLK) {
            const int bid = id - NHS_BLK - NG_BLK;
            W = Wk; WT = WkT; D = DH;
            d0 = (bid & 31) * 32; p0 = (bid >> 5) * 32;     // 32 x 8
        } else {
            const int bid = id - NHS_BLK - NG_BLK - NWK_BLK;
            W = Wq; WT = WqT; D = DG;
            d0 = (bid % 24) * 32; p0 = (bid / 24) * 32;     // 24 x 8
        }
        const int tx = threadIdx.x & 31, ty = threadIdx.x >> 5;
        #pragma unroll
        for (int j = 0; j < 4; ++j)
            tf[ty + 8 * j][tx] = W[(long)(d0 + ty + 8 * j) * DP + p0 + tx];
        __syncthreads();
        #pragma unroll
        for (int j = 0; j < 4; ++j)
            WT[(long)(p0 + ty + 8 * j) * D + d0 + tx] = f2b(tf[tx][ty + 8 * j]);
    }
}

// ---------------------------------------------------------------------------
// Z = sum of 2 bf16 partials -> fp32. 8 elems/thread.
// ---------------------------------------------------------------------------
__global__ __launch_bounds__(256) void reduce_add2(
    const unsigned short* __restrict__ P, long sP, float* __restrict__ Zo)
{
    long i = ((long)blockIdx.x * 256 + threadIdx.x) * 8;
    u16x8 a = *(const u16x8*)&P[i];
    u16x8 b = *(const u16x8*)&P[i + sP];
    float4 o0, o1;
    o0.x = b2f(a[0]) + b2f(b[0]);
    o0.y = b2f(a[1]) + b2f(b[1]);
    o0.z = b2f(a[2]) + b2f(b[2]);
    o0.w = b2f(a[3]) + b2f(b[3]);
    o1.x = b2f(a[4]) + b2f(b[4]);
    o1.y = b2f(a[5]) + b2f(b[5]);
    o1.z = b2f(a[6]) + b2f(b[6]);
    o1.w = b2f(a[7]) + b2f(b[7]);
    *(float4*)&Zo[i] = o0;
    *(float4*)&Zo[i + 4] = o1;
}

// ---------------------------------------------------------------------------
// Row softmax over bf16 logits: 2048/row, 256 threads, 8 elems/thread.
// ---------------------------------------------------------------------------
__global__ __launch_bounds__(256) void softmax_kernel(
    const unsigned short* __restrict__ S, unsigned short* __restrict__ Ab)
{
    const u16x8* row8 = (const u16x8*)(S + (long)blockIdx.x * LKEYS);
    u16x8* out8 = (u16x8*)(Ab + (long)blockIdx.x * LKEYS);
    const int tid = threadIdx.x;
    __shared__ float red[4];

    u16x8 v = row8[tid];
    float x[8];
    #pragma unroll
    for (int j = 0; j < 8; ++j) x[j] = b2f(v[j]);

    float m = fmaxf(fmaxf(fmaxf(x[0], x[1]), fmaxf(x[2], x[3])),
                    fmaxf(fmaxf(x[4], x[5]), fmaxf(x[6], x[7])));
    #pragma unroll
    for (int off = 32; off > 0; off >>= 1) m = fmaxf(m, __shfl_xor(m, off));
    if ((tid & 63) == 0) red[tid >> 6] = m;
    __syncthreads();
    m = fmaxf(fmaxf(red[0], red[1]), fmaxf(red[2], red[3]));

    float e[8], s = 0.f;
    #pragma unroll
    for (int j = 0; j < 8; ++j) { e[j] = __expf(x[j] - m); s += e[j]; }
    #pragma unroll
    for (int off = 32; off > 0; off >>= 1) s += __shfl_xor(s, off);
    __syncthreads();
    if ((tid & 63) == 0) red[tid >> 6] = s;
    __syncthreads();
    s = red[0] + red[1] + red[2] + red[3];

    float inv = 1.0f / s;
    u16x8 o;
    #pragma unroll
    for (int j = 0; j < 8; ++j) o[j] = f2b(e[j] * inv);
    out8[tid] = o;
}

// ---------------------------------------------------------------------------
extern "C" void kernel_launch(void* const* d_in, const int* in_sizes, int n_in,
                              void* d_out, int out_size, void* d_ws, size_t ws_size,
                              hipStream_t stream)
{
    const float* H    = (const float*)d_in[0];  // [B,L,Dh]
    const float* G    = (const float*)d_in[1];  // [B,T,Dg]
    const int*   mask = (const int*)  d_in[2];  // [B,L]
    const float* Wk   = (const float*)d_in[3];  // [Dh,Dp]
    const float* Wq   = (const float*)d_in[4];  // [Dg,Dp]
    float*       Z    = (float*)d_out;          // [B,T,Dh]

    // Workspace (101.6 MB). u16 offsets:
    // WkT|WqT|Ab|Kb|Qb|Gb|HbT|X  where X (33.5 MB) = Hb -> S(bf16) -> Zp(2x bf16)
    unsigned short* WkT = (unsigned short*)d_ws;      // 256*1024
    unsigned short* WqT = WkT + 262144;               // 256*768
    unsigned short* Ab  = WqT + 196608;               // 8*512*2048 bf16
    unsigned short* Kb  = Ab  + 8388608;              // 8*2048*256
    unsigned short* Qb  = Kb  + 4194304;              // 8*512*256
    unsigned short* Gb  = Qb  + 1048576;              // 8*512*768
    unsigned short* HbT = Gb  + 3145728;              // 8*1024*2048
    unsigned short* Hb  = HbT + 16777216;             // X: 8*2048*1024 u16
    unsigned short* S   = Hb;                         // X: 8*512*2048 u16 (bf16)
    unsigned short* Zp  = Hb;                         // X: 2 * 8*512*1024 u16
    const long sZp = (long)BATCH * TQ * DH;           // per-PART stride (u16 elems)
    const long sZb = (long)TQ * DH;                   // per-BATCH stride (u16 elems)

    // 1) prep: flat H->Hb, G->Gb, W transposes (HbT in launch 2, overlapped)
    prep_all<<<NHS_BLK + NG_BLK + NWK_BLK + NWQ_BLK, 256, 0, stream>>>(
        H, G, Wk, Wq, Hb, Gb, WkT, WqT);

    // 2) K-proj + Q-proj + Hb->HbT transpose (overlapped): 640 + 4096 blocks.
    proj_kq_ht<<<NPROJ + 4096, 256, 0, stream>>>(Hb, WkT, Kb, Gb, WqT, Qb, HbT);

    // 3) logits -> S bf16 (scale+mask) : per batch 512x2048x256. 3D swz.
    gemm_bf16_p<128, 128, 3, 2, 1><<<dim3(16, 4, BATCH), 256, 0, stream>>>(
        Qb, Kb, mask, S, DP, DP, DP, LKEYS,
        (long)TQ * DP, (long)LKEYS * DP, (long)TQ * LKEYS, (long)LKEYS, 0, SCALE);

    // 4) softmax over L (bf16 in) -> bf16 alpha (S dead after; Zp overlays X)
    softmax_kernel<<<BATCH * TQ, 256, 0, stream>>>(S, Ab);

    // 5) Z partials = Ab @ HbT^T, KSPLIT=2, depth-2 counted vmcnt, 3D swz.
    gemm_bf16_p<128, 128, 1, 2, 2><<<dim3(8, 4, 2 * BATCH), 256, 0, stream>>>(
        Ab, HbT, nullptr, Zp, LKEYS / 2, LKEYS, LKEYS, DH,
        (long)TQ * LKEYS, (long)DH * LKEYS, sZb, 0, sZp, 1.f);

    // 6) Z = Zp[0] + Zp[1]
    reduce_add2<<<(int)(sZp / 8 / 256), 256, 0, stream>>>(Zp, sZp, Z);
}